// Round 4
// baseline (3997.584 us; speedup 1.0000x reference)
//
#include <hip/hip_runtime.h>
#include <hip/hip_bf16.h>
#include <stdint.h>
#include <algorithm>

// Sparse conv encoder, gather formulation, FP32 inputs/outputs.
// For each layer & offset k, out_idx[k] is injective and sorted -> per-block
// binary search resolves gather index table[k][row] on the fly (zero ws for
// tables). Features/weights staged to LDS as bf16 (f32 accumulate);
// intermediates x/y/z stored bf16 in ws (~50 MB, proven to fit: the round-2/3
// ws-size diag never fired). c1/c2 read out0/out1 from d_out in fp32.

#define DI __device__ __forceinline__

DI float u2f(uint32_t u){ union{uint32_t i;float f;}v; v.i=u; return v.f; }
DI float bf2f(uint16_t u){ return u2f(((uint32_t)u)<<16); }
DI uint16_t f2bf(float x){
  union{float f;uint32_t i;}v; v.f=x;
  uint32_t r = v.i + 0x7fffu + ((v.i>>16)&1u);
  return (uint16_t)(r>>16);
}
DI uint32_t pack2(float a, float b){
  return (uint32_t)f2bf(a) | ((uint32_t)f2bf(b) << 16);
}

// lower_bound over sorted om[0..M): return p with om[p]==row else -1.
DI int bsearch_row(const int* __restrict__ om, int M, int row){
  int lo = 0, hi = M;
  while (lo < hi){ int mid = (lo+hi)>>1; if (om[mid] < row) lo = mid+1; else hi = mid; }
  return (lo < M && om[lo] == row) ? lo : -1;
}

__global__ __launch_bounds__(256) void diag_kernel(float* __restrict__ out, long n, float c){
  long i = (long)blockIdx.x*256 + threadIdx.x;
  if (i < n) out[i] = c;
}

// c0: Cin=1 -> Cout=64, fp32 in, bf16 out. Block = 4 rows x 64 couts.
__global__ __launch_bounds__(256) void gconv_c0_kernel(
    const float* __restrict__ feats, const float* __restrict__ w,
    const float* __restrict__ bias,
    const int* __restrict__ im, const int* __restrict__ om, int M,
    uint16_t* __restrict__ out, int n_in, int n_out){
  __shared__ float w_s[576];
  __shared__ int gi_s[36];
  const int tid = threadIdx.x;
  for (int i = tid; i < 576; i += 256) w_s[i] = w[i];
  const int base = blockIdx.x * 4;
  if (tid < 36){
    int p = tid / 9, k = tid - p*9;
    int row = base + p, gi = -1;
    if (row < n_out){
      int pos = bsearch_row(om + (long)k*M, M, row);
      if (pos >= 0){
        int ii = im[(long)k*M + pos];
        if (ii >= 0 && ii < n_in) gi = ii;
      }
    }
    gi_s[p*9 + k] = gi;
  }
  __syncthreads();
  int r4 = tid >> 6, c = tid & 63;
  int row = base + r4;
  if (row >= n_out) return;
  float a = bias[c];
  #pragma unroll
  for (int k = 0; k < 9; k++){
    int gi = gi_s[r4*9 + k];
    if (gi >= 0) a += feats[gi] * w_s[k*64 + c];
  }
  out[(long)row*64 + c] = f2bf(a);
}

// Generic gather conv: CIN in {64,128} -> Cout=128.
// Block = 16 rows x 16 cout-groups (8 couts each). 144 upfront binary
// searches resolve all (k,row) gather indices per block.
// INBF: input features bf16 (ws) vs fp32 (d_in/d_out).
// OUTBF: write bf16 (ws) vs fp32 (d_out).
template<int CIN, bool RELU, bool INBF, bool OUTBF>
__global__ __launch_bounds__(256) void gconv_kernel(
    const void* __restrict__ feats_v, const float* __restrict__ w,
    const float* __restrict__ bias,
    const int* __restrict__ im, const int* __restrict__ om, int M,
    void* __restrict__ out_v, int n_in, int n_out){
  const int tid = threadIdx.x;
  const int ob  = blockIdx.x * 16;
  const int p   = tid >> 4;     // row in block
  const int j   = tid & 15;     // cout group
  const int row = ob + p;
  const int co  = j * 8;

  __shared__ __align__(16) uint16_t w_s[CIN*128];       // bf16 weights
  __shared__ __align__(16) uint16_t f_s[16*(CIN+8)];    // bf16 features
  __shared__ int gi_s[9*16];

  if (tid < 144){
    int k = tid >> 4, pr = tid & 15;
    int r = ob + pr, gi = -1;
    if (r < n_out){
      int pos = bsearch_row(om + (long)k*M, M, r);
      if (pos >= 0){
        int ii = im[(long)k*M + pos];
        if (ii >= 0 && ii < n_in) gi = ii;
      }
    }
    gi_s[tid] = gi;
  }
  __syncthreads();

  float a[8];
  #pragma unroll
  for (int q = 0; q < 8; q++) a[q] = 0.f;

  for (int k = 0; k < 9; k++){
    // Stage w[k] (CIN x 128 fp32 global) -> bf16 LDS.
    {
      const float4* wg = (const float4*)(w + (long)k*CIN*128);
      #pragma unroll
      for (int idx = tid; idx < CIN*128/4; idx += 256){
        float4 v = wg[idx];
        uint2 o; o.x = pack2(v.x, v.y); o.y = pack2(v.z, v.w);
        *(uint2*)(&w_s[idx*4]) = o;
      }
    }
    // Gather this block's 16 input rows -> bf16 LDS (zeros where no pair).
    {
      int gi = gi_s[k*16 + p];
      if (INBF){
        const uint16_t* f = (const uint16_t*)feats_v;
        if (CIN == 128){
          uint4 v = make_uint4(0,0,0,0);
          if (gi >= 0) v = *(const uint4*)(f + (long)gi*128 + j*8);
          *(uint4*)(&f_s[p*(CIN+8) + j*8]) = v;
        } else {
          uint2 v = make_uint2(0,0);
          if (gi >= 0) v = *(const uint2*)(f + (long)gi*64 + j*4);
          *(uint2*)(&f_s[p*(CIN+8) + j*4]) = v;
        }
      } else {
        const float* f = (const float*)feats_v;
        if (CIN == 128){
          float4 v0 = make_float4(0,0,0,0), v1 = v0;
          if (gi >= 0){
            v0 = *(const float4*)(f + (long)gi*128 + j*8);
            v1 = *(const float4*)(f + (long)gi*128 + j*8 + 4);
          }
          uint4 o;
          o.x = pack2(v0.x, v0.y); o.y = pack2(v0.z, v0.w);
          o.z = pack2(v1.x, v1.y); o.w = pack2(v1.z, v1.w);
          *(uint4*)(&f_s[p*(CIN+8) + j*8]) = o;
        } else {
          float4 v0 = make_float4(0,0,0,0);
          if (gi >= 0) v0 = *(const float4*)(f + (long)gi*64 + j*4);
          uint2 o; o.x = pack2(v0.x, v0.y); o.y = pack2(v0.z, v0.w);
          *(uint2*)(&f_s[p*(CIN+8) + j*4]) = o;
        }
      }
    }
    __syncthreads();

    const uint16_t* frow = &f_s[p*(CIN+8)];
    #pragma unroll 4
    for (int c = 0; c < CIN; c += 2){
      uint32_t fp2 = *(const uint32_t*)(frow + c);
      float f0 = u2f(fp2 << 16);
      float f1 = u2f(fp2 & 0xffff0000u);
      uint4 w0 = *(const uint4*)(&w_s[(c  )*128 + co]);
      uint4 w1 = *(const uint4*)(&w_s[(c+1)*128 + co]);
      const uint32_t* wp0 = (const uint32_t*)&w0;
      const uint32_t* wp1 = (const uint32_t*)&w1;
      #pragma unroll
      for (int q = 0; q < 4; q++){
        a[2*q  ] += f0 * u2f(wp0[q] << 16);
        a[2*q+1] += f0 * u2f(wp0[q] & 0xffff0000u);
        a[2*q  ] += f1 * u2f(wp1[q] << 16);
        a[2*q+1] += f1 * u2f(wp1[q] & 0xffff0000u);
      }
    }
    __syncthreads();
  }

  if (row < n_out){
    float4 b0 = *(const float4*)(bias + co);
    float4 b1 = *(const float4*)(bias + co + 4);
    a[0]+=b0.x; a[1]+=b0.y; a[2]+=b0.z; a[3]+=b0.w;
    a[4]+=b1.x; a[5]+=b1.y; a[6]+=b1.z; a[7]+=b1.w;
    if (RELU){
      #pragma unroll
      for (int q = 0; q < 8; q++) a[q] = a[q] > 0.f ? a[q] : 0.f;
    }
    if (OUTBF){
      uint16_t* dst = (uint16_t*)out_v + (long)row*128 + co;
      uint4 o;
      o.x = pack2(a[0], a[1]); o.y = pack2(a[2], a[3]);
      o.z = pack2(a[4], a[5]); o.w = pack2(a[6], a[7]);
      *(uint4*)dst = o;
    } else {
      float* dst = (float*)out_v + (long)row*128 + co;
      *(float4*)(dst)   = make_float4(a[0],a[1],a[2],a[3]);
      *(float4*)(dst+4) = make_float4(a[4],a[5],a[6],a[7]);
    }
  }
}

static inline long cdivl(long a, long b){ return (a + b - 1) / b; }

extern "C" void kernel_launch(void* const* d_in, const int* in_sizes, int n_in_args,
                              void* d_out, int out_size, void* d_ws, size_t ws_size,
                              hipStream_t stream) {
  const float* feats = (const float*)d_in[0];
  const float* w_c0 = (const float*)d_in[1];
  const float* b_c0 = (const float*)d_in[2];
  const int* in_c0  = (const int*)d_in[3];
  const int* out_c0 = (const int*)d_in[4];
  const float* w_d0 = (const float*)d_in[5];
  const float* b_d0 = (const float*)d_in[6];
  const int* in_d0  = (const int*)d_in[7];
  const int* out_d0 = (const int*)d_in[8];
  const float* w_c1 = (const float*)d_in[9];
  const float* b_c1 = (const float*)d_in[10];
  const int* in_c1  = (const int*)d_in[11];
  const int* out_c1 = (const int*)d_in[12];
  const float* w_d1 = (const float*)d_in[13];
  const float* b_d1 = (const float*)d_in[14];
  const int* in_d1  = (const int*)d_in[15];
  const int* out_d1 = (const int*)d_in[16];
  const float* w_c2 = (const float*)d_in[17];
  const float* b_c2 = (const float*)d_in[18];
  const int* in_c2  = (const int*)d_in[19];
  const int* out_c2 = (const int*)d_in[20];
  const float* w_d2 = (const float*)d_in[21];
  const float* b_d2 = (const float*)d_in[22];
  const int* in_d2  = (const int*)d_in[23];
  const int* out_d2 = (const int*)d_in[24];

  const int n0   = in_sizes[0];
  const int M_c0 = in_sizes[3]  / 9;
  const int M_d0 = in_sizes[7]  / 9;
  const int M_c1 = in_sizes[11] / 9;
  const int M_d1 = in_sizes[15] / 9;
  const int M_c2 = in_sizes[19] / 9;
  const int M_d2 = in_sizes[23] / 9;
  const int n1   = M_c1;               // stride-1 center offset pairs every output
  const int n2   = M_c2;
  const int n3   = out_size/128 - n1 - n2;

  bool sane = n0 > 0 && out_size % 128 == 0 &&
              in_sizes[3]%9==0 && in_sizes[7]%9==0 && in_sizes[11]%9==0 &&
              in_sizes[15]%9==0 && in_sizes[19]%9==0 && in_sizes[23]%9==0 &&
              M_c0 > 0 && M_d0 > 0 && M_d1 > 0 && M_d2 > 0 &&
              n1 > 0 && n2 > 0 && n3 > 0 && n3 <= out_size/128;

  long maxElems = (long)n0*64;
  if ((long)n1*128 > maxElems) maxElems = (long)n1*128;
  if ((long)n2*128 > maxElems) maxElems = (long)n2*128;
  long need = maxElems * 2;   // bf16 intermediate buffer

  if (!sane || ws_size < (size_t)need + 256){
    float C = (float)(16 + (int)std::min<size_t>(ws_size >> 20, (size_t)100000));
    if (!sane) C *= 1099511627776.0f;   // 2^40 flag
    diag_kernel<<<cdivl(out_size,256),256,0,stream>>>((float*)d_out, out_size, C);
    return;
  }

  uint16_t* fbuf = (uint16_t*)d_ws;    // aliased x (n0,64) / y (n1,128) / z (n2,128)
  float* out2 = (float*)d_out;                 // (n3,128)
  float* out1 = out2 + (long)n3*128;           // (n2,128)
  float* out0 = out1 + (long)n2*128;           // (n1,128)
  uint16_t* x = fbuf; uint16_t* y = fbuf; uint16_t* z = fbuf;

  // c0: feats (fp32) -> x (bf16)
  gconv_c0_kernel<<<cdivl(n0,4),256,0,stream>>>(
      feats, w_c0, b_c0, in_c0, out_c0, M_c0, x, n0, n0);
  // d0: x (bf16) -> out0 (fp32), relu
  gconv_kernel<64,true,true,false><<<cdivl(n1,16),256,0,stream>>>(
      x, w_d0, b_d0, in_d0, out_d0, M_d0, out0, n0, n1);
  // c1: out0 (fp32) -> y (bf16)
  gconv_kernel<128,false,false,true><<<cdivl(n1,16),256,0,stream>>>(
      out0, w_c1, b_c1, in_c1, out_c1, M_c1, y, n1, n1);
  // d1: y (bf16) -> out1 (fp32), relu
  gconv_kernel<128,true,true,false><<<cdivl(n2,16),256,0,stream>>>(
      y, w_d1, b_d1, in_d1, out_d1, M_d1, out1, n1, n2);
  // c2: out1 (fp32) -> z (bf16)
  gconv_kernel<128,false,false,true><<<cdivl(n2,16),256,0,stream>>>(
      out1, w_c2, b_c2, in_c2, out_c2, M_c2, z, n2, n2);
  // d2: z (bf16) -> out2 (fp32)
  gconv_kernel<128,false,true,false><<<cdivl(n3,16),256,0,stream>>>(
      z, w_d2, b_d2, in_d2, out_d2, M_d2, out2, n2, n3);
}

// Round 5
// 1174.962 us; speedup vs baseline: 3.4023x; 3.4023x over previous
//
#include <hip/hip_runtime.h>
#include <hip/hip_bf16.h>
#include <stdint.h>
#include <algorithm>

// Sparse conv encoder, MFMA gather-GEMM formulation. fp32 in/out, bf16
// compute (verified numerics: R4 absmax 0.0156 << 0.0925 threshold).
// Per layer & offset k, out_idx[k] is injective+sorted -> per-block binary
// search resolves gather row; features + transposed weights staged to LDS
// (bf16, stride CIN+8 => 272B row pitch => 2-way bank aliasing = free);
// inner loop: v_mfma_f32_16x16x32_bf16, wave tile 64x64 (16 acc tiles),
// block tile 128 rows x 128 couts (4 waves, 2x2).
// Weights pre-transposed to bf16 in ws by prep kernel (1.33 MB) when ws_size
// allows; else in-kernel transpose fallback. Intermediates x/y/z bf16 in ws
// (aliased, disjoint lifetimes).

#define DI __device__ __forceinline__

typedef __attribute__((ext_vector_type(8))) short bf16x8;
typedef __attribute__((ext_vector_type(4))) float f32x4;

DI float u2f(uint32_t u){ union{uint32_t i;float f;}v; v.i=u; return v.f; }
DI uint16_t f2bf(float x){
  union{float f;uint32_t i;}v; v.f=x;
  uint32_t r = v.i + 0x7fffu + ((v.i>>16)&1u);
  return (uint16_t)(r>>16);
}
DI uint32_t pack2(float a, float b){
  return (uint32_t)f2bf(a) | ((uint32_t)f2bf(b) << 16);
}

// lower_bound over sorted om[0..M): return p with om[p]==row else -1.
DI int bsearch_row(const int* __restrict__ om, int M, int row){
  int lo = 0, hi = M;
  while (lo < hi){ int mid = (lo+hi)>>1; if (om[mid] < row) lo = mid+1; else hi = mid; }
  return (lo < M && om[lo] == row) ? lo : -1;
}

__global__ __launch_bounds__(256) void diag_kernel(float* __restrict__ out, long n, float c){
  long i = (long)blockIdx.x*256 + threadIdx.x;
  if (i < n) out[i] = c;
}

// w (9,cin,128) fp32 -> wtb (9,128,cin) bf16 (transposed, for B-fragment rows).
__global__ __launch_bounds__(256) void prep_w_kernel(
    const float* __restrict__ w, uint16_t* __restrict__ wtb, int cin){
  long idx = (long)blockIdx.x*256 + threadIdx.x;
  long total = 9L*128*cin;
  if (idx >= total) return;
  int k = (int)(idx / (128*cin));
  int rem = (int)(idx % (128*cin));
  int cout = rem / cin, ci = rem % cin;
  wtb[idx] = f2bf(w[((long)k*cin + ci)*128 + cout]);
}

// c0: Cin=1 -> Cout=64, fp32 in, bf16 out. Block = 4 rows x 64 couts.
__global__ __launch_bounds__(256) void gconv_c0_kernel(
    const float* __restrict__ feats, const float* __restrict__ w,
    const float* __restrict__ bias,
    const int* __restrict__ im, const int* __restrict__ om, int M,
    uint16_t* __restrict__ out, int n_in, int n_out){
  __shared__ float w_s[576];
  __shared__ int gi_s[36];
  const int tid = threadIdx.x;
  for (int i = tid; i < 576; i += 256) w_s[i] = w[i];
  const int base = blockIdx.x * 4;
  if (tid < 36){
    int p = tid / 9, k = tid - p*9;
    int row = base + p, gi = -1;
    if (row < n_out){
      int pos = bsearch_row(om + (long)k*M, M, row);
      if (pos >= 0){
        int ii = im[(long)k*M + pos];
        if (ii >= 0 && ii < n_in) gi = ii;
      }
    }
    gi_s[p*9 + k] = gi;
  }
  __syncthreads();
  int r4 = tid >> 6, c = tid & 63;
  int row = base + r4;
  if (row >= n_out) return;
  float a = bias[c];
  #pragma unroll
  for (int k = 0; k < 9; k++){
    int gi = gi_s[r4*9 + k];
    if (gi >= 0) a += feats[gi] * w_s[k*64 + c];
  }
  out[(long)row*64 + c] = f2bf(a);
}

// MFMA gather conv: CIN in {64,128} -> 128 couts.
// Block 256 thr = 4 waves (2x2): wave tile 64 rows x 64 couts.
template<int CIN, bool RELU, bool INBF, bool OUTBF>
__global__ __launch_bounds__(256,2) void mconv_kernel(
    const void* __restrict__ feats_v, const float* __restrict__ w,
    const uint16_t* __restrict__ wtb, int use_wtb,
    const float* __restrict__ bias,
    const int* __restrict__ im, const int* __restrict__ om, int M,
    void* __restrict__ out_v, int n_in, int n_out){
  const int tid = threadIdx.x;
  const int rb  = blockIdx.x * 128;
  constexpr int FS = CIN + 8;             // padded LDS pitch (bf16 elems)

  __shared__ __align__(16) uint16_t f_s[128*FS];
  __shared__ __align__(16) uint16_t wt_s[128*FS];
  __shared__ int gi_s[9*128];
  __shared__ int kval[9];

  if (tid < 9) kval[tid] = 0;
  __syncthreads();
  for (int idx = tid; idx < 9*128; idx += 256){
    int k = idx >> 7, r = idx & 127;
    int row = rb + r, gi = -1;
    if (row < n_out){
      int pos = bsearch_row(om + (long)k*M, M, row);
      if (pos >= 0){
        int ii = im[(long)k*M + pos];
        if (ii >= 0 && ii < n_in) gi = ii;
      }
    }
    gi_s[idx] = gi;
    if (gi >= 0) kval[k] = 1;     // benign race: all write 1
  }
  __syncthreads();

  const int lane = tid & 63;
  const int wv   = tid >> 6;
  const int wr   = (wv & 1) * 64;       // wave row base (in-block)
  const int wc   = (wv >> 1) * 64;      // wave cout base
  const int l16  = lane & 15;
  const int quad = lane >> 4;

  f32x4 acc[4][4];
  #pragma unroll
  for (int i = 0; i < 4; i++)
    #pragma unroll
    for (int j = 0; j < 4; j++)
      acc[i][j] = (f32x4){0.f,0.f,0.f,0.f};

  for (int k = 0; k < 9; k++){
    if (!kval[k]) continue;
    // ---- stage weights (transposed bf16: wt_s[cout][cin]) ----
    if (use_wtb){
      const uint4* wg = (const uint4*)(wtb + (long)k*128*CIN);
      #pragma unroll
      for (int idx = tid; idx < 128*CIN/8; idx += 256){
        int cout = idx/(CIN/8), seg = idx%(CIN/8);
        *(uint4*)(&wt_s[cout*FS + seg*8]) = wg[idx];
      }
    } else {
      const float4* wg = (const float4*)(w + (long)k*CIN*128);
      #pragma unroll
      for (int idx = tid; idx < CIN*32; idx += 256){
        int ci = idx >> 5, c4 = (idx & 31)*4;
        float4 v = wg[idx];
        wt_s[(c4+0)*FS + ci] = f2bf(v.x);
        wt_s[(c4+1)*FS + ci] = f2bf(v.y);
        wt_s[(c4+2)*FS + ci] = f2bf(v.z);
        wt_s[(c4+3)*FS + ci] = f2bf(v.w);
      }
    }
    // ---- stage gathered features (f_s[row][cin], zeros where no pair) ----
    if (INBF){
      const uint16_t* f = (const uint16_t*)feats_v;
      #pragma unroll
      for (int idx = tid; idx < 128*CIN/8; idx += 256){
        int r = idx/(CIN/8), seg = idx%(CIN/8);
        int gi = gi_s[(k<<7)+r];
        uint4 v = make_uint4(0,0,0,0);
        if (gi >= 0) v = *(const uint4*)(f + (long)gi*CIN + seg*8);
        *(uint4*)(&f_s[r*FS + seg*8]) = v;
      }
    } else {
      const float* f = (const float*)feats_v;
      #pragma unroll
      for (int idx = tid; idx < 128*CIN/8; idx += 256){
        int r = idx/(CIN/8), seg = idx%(CIN/8);
        int gi = gi_s[(k<<7)+r];
        uint4 o = make_uint4(0,0,0,0);
        if (gi >= 0){
          float4 v0 = *(const float4*)(f + (long)gi*CIN + seg*8);
          float4 v1 = *(const float4*)(f + (long)gi*CIN + seg*8 + 4);
          o.x = pack2(v0.x,v0.y); o.y = pack2(v0.z,v0.w);
          o.z = pack2(v1.x,v1.y); o.w = pack2(v1.z,v1.w);
        }
        *(uint4*)(&f_s[r*FS + seg*8]) = o;
      }
    }
    __syncthreads();

    // ---- MFMA inner loop over K chunks of 32 ----
    #pragma unroll
    for (int ch = 0; ch < CIN/32; ch++){
      bf16x8 af[4], bfr[4];
      #pragma unroll
      for (int t = 0; t < 4; t++){
        af[t]  = *(const bf16x8*)(&f_s [(wr + t*16 + l16)*FS + ch*32 + quad*8]);
        bfr[t] = *(const bf16x8*)(&wt_s[(wc + t*16 + l16)*FS + ch*32 + quad*8]);
      }
      #pragma unroll
      for (int rt = 0; rt < 4; rt++)
        #pragma unroll
        for (int ct = 0; ct < 4; ct++)
          acc[rt][ct] = __builtin_amdgcn_mfma_f32_16x16x32_bf16(
              af[rt], bfr[ct], acc[rt][ct], 0, 0, 0);
    }
    __syncthreads();
  }

  // ---- epilogue: bias (+relu), store fp32 or bf16 ----
  #pragma unroll
  for (int ct = 0; ct < 4; ct++){
    int cout = wc + ct*16 + l16;
    float bv = bias[cout];
    #pragma unroll
    for (int rt = 0; rt < 4; rt++){
      #pragma unroll
      for (int r = 0; r < 4; r++){
        int row = rb + wr + rt*16 + quad*4 + r;
        if (row < n_out){
          float v = acc[rt][ct][r] + bv;
          if (RELU) v = v > 0.f ? v : 0.f;
          if (OUTBF) ((uint16_t*)out_v)[(long)row*128 + cout] = f2bf(v);
          else       ((float*)   out_v)[(long)row*128 + cout] = v;
        }
      }
    }
  }
}

static inline long cdivl(long a, long b){ return (a + b - 1) / b; }

extern "C" void kernel_launch(void* const* d_in, const int* in_sizes, int n_in_args,
                              void* d_out, int out_size, void* d_ws, size_t ws_size,
                              hipStream_t stream) {
  const float* feats = (const float*)d_in[0];
  const float* w_c0 = (const float*)d_in[1];
  const float* b_c0 = (const float*)d_in[2];
  const int* in_c0  = (const int*)d_in[3];
  const int* out_c0 = (const int*)d_in[4];
  const float* w_d0 = (const float*)d_in[5];
  const float* b_d0 = (const float*)d_in[6];
  const int* in_d0  = (const int*)d_in[7];
  const int* out_d0 = (const int*)d_in[8];
  const float* w_c1 = (const float*)d_in[9];
  const float* b_c1 = (const float*)d_in[10];
  const int* in_c1  = (const int*)d_in[11];
  const int* out_c1 = (const int*)d_in[12];
  const float* w_d1 = (const float*)d_in[13];
  const float* b_d1 = (const float*)d_in[14];
  const int* in_d1  = (const int*)d_in[15];
  const int* out_d1 = (const int*)d_in[16];
  const float* w_c2 = (const float*)d_in[17];
  const float* b_c2 = (const float*)d_in[18];
  const int* in_c2  = (const int*)d_in[19];
  const int* out_c2 = (const int*)d_in[20];
  const float* w_d2 = (const float*)d_in[21];
  const float* b_d2 = (const float*)d_in[22];
  const int* in_d2  = (const int*)d_in[23];
  const int* out_d2 = (const int*)d_in[24];

  const int n0   = in_sizes[0];
  const int M_c0 = in_sizes[3]  / 9;
  const int M_d0 = in_sizes[7]  / 9;
  const int M_c1 = in_sizes[11] / 9;
  const int M_d1 = in_sizes[15] / 9;
  const int M_c2 = in_sizes[19] / 9;
  const int M_d2 = in_sizes[23] / 9;
  const int n1   = M_c1;
  const int n2   = M_c2;
  const int n3   = out_size/128 - n1 - n2;

  bool sane = n0 > 0 && out_size % 128 == 0 &&
              M_c0 > 0 && M_d0 > 0 && M_d1 > 0 && M_d2 > 0 &&
              n1 > 0 && n2 > 0 && n3 > 0;

  long maxElems = (long)n0*64;
  if ((long)n1*128 > maxElems) maxElems = (long)n1*128;
  if ((long)n2*128 > maxElems) maxElems = (long)n2*128;
  long fbytes = (maxElems*2 + 255)/256*256;

  if (!sane || ws_size < (size_t)fbytes + 256){
    float C = (float)(16 + (int)std::min<size_t>(ws_size >> 20, (size_t)100000));
    if (!sane) C *= 1099511627776.0f;
    diag_kernel<<<cdivl(out_size,256),256,0,stream>>>((float*)d_out, out_size, C);
    return;
  }

  // ws: [ fbuf (aliased x/y/z bf16) | wtb_d0 | wtb_c1 | wtb_d1 | wtb_c2 | wtb_d2 ]
  uint16_t* fbuf = (uint16_t*)d_ws;
  long wt64  = 9L*128*64;    // elems
  long wt128 = 9L*128*128;
  long wbytes = (wt64 + 4*wt128) * 2;
  int use_wtb = (ws_size >= (size_t)(fbytes + wbytes + 512)) ? 1 : 0;

  uint16_t* wtb_d0 = (uint16_t*)((char*)d_ws + fbytes);
  uint16_t* wtb_c1 = wtb_d0 + wt64;
  uint16_t* wtb_d1 = wtb_c1 + wt128;
  uint16_t* wtb_c2 = wtb_d1 + wt128;
  uint16_t* wtb_d2 = wtb_c2 + wt128;

  float* out2 = (float*)d_out;
  float* out1 = out2 + (long)n3*128;
  float* out0 = out1 + (long)n2*128;
  uint16_t* x = fbuf; uint16_t* y = fbuf; uint16_t* z = fbuf;

  if (use_wtb){
    prep_w_kernel<<<cdivl(9L*128*64,256),256,0,stream>>>(w_d0, wtb_d0, 64);
    prep_w_kernel<<<cdivl(9L*128*128,256),256,0,stream>>>(w_c1, wtb_c1, 128);
    prep_w_kernel<<<cdivl(9L*128*128,256),256,0,stream>>>(w_d1, wtb_d1, 128);
    prep_w_kernel<<<cdivl(9L*128*128,256),256,0,stream>>>(w_c2, wtb_c2, 128);
    prep_w_kernel<<<cdivl(9L*128*128,256),256,0,stream>>>(w_d2, wtb_d2, 128);
  }

  // c0: feats fp32 -> x bf16
  gconv_c0_kernel<<<cdivl(n0,4),256,0,stream>>>(
      feats, w_c0, b_c0, in_c0, out_c0, M_c0, x, n0, n0);
  // d0: x bf16 -> out0 fp32, relu
  mconv_kernel<64,true,true,false><<<cdivl(n1,128),256,0,stream>>>(
      x, w_d0, wtb_d0, use_wtb, b_d0, in_d0, out_d0, M_d0, out0, n0, n1);
  // c1: out0 fp32 -> y bf16
  mconv_kernel<128,false,false,true><<<cdivl(n1,128),256,0,stream>>>(
      out0, w_c1, wtb_c1, use_wtb, b_c1, in_c1, out_c1, M_c1, y, n1, n1);
  // d1: y bf16 -> out1 fp32, relu
  mconv_kernel<128,true,true,false><<<cdivl(n2,128),256,0,stream>>>(
      y, w_d1, wtb_d1, use_wtb, b_d1, in_d1, out_d1, M_d1, out1, n1, n2);
  // c2: out1 fp32 -> z bf16
  mconv_kernel<128,false,false,true><<<cdivl(n2,128),256,0,stream>>>(
      out1, w_c2, wtb_c2, use_wtb, b_c2, in_c2, out_c2, M_c2, z, n2, n2);
  // d2: z bf16 -> out2 fp32
  mconv_kernel<128,false,true,false><<<cdivl(n3,128),256,0,stream>>>(
      z, w_d2, wtb_d2, use_wtb, b_d2, in_d2, out_d2, M_d2, out2, n2, n3);
}

// Round 6
// 740.518 us; speedup vs baseline: 5.3984x; 1.5867x over previous
//
#include <hip/hip_runtime.h>
#include <hip/hip_bf16.h>
#include <stdint.h>
#include <algorithm>

// Sparse conv encoder, MFMA gather-GEMM + scattered inverse tables.
// Per layer & offset k, out_idx[k] is injective -> build table[k][o]=in_row
// (-1 if none) with coalesced scatter (init+build, ~us each), then convs read
// gather rows with ONE coalesced load instead of an 18-step binary search
// (R5: c0 latency-bound at 321us, VALUBusy 14%, HBM 2.9%).
// Binary-search fallback retained (use_tab=0) if ws can't hold the table.
// mconv: v_mfma_f32_16x16x32_bf16, block 128x128 (4 waves 2x2, wave 64x64),
// LDS pitch CIN+8 (272B -> 2-way bank aliasing = free). fp32 in/out, bf16
// compute (R4/R5 verified: absmax 0.0156 << 0.0925).

#define DI __device__ __forceinline__

typedef __attribute__((ext_vector_type(8))) short bf16x8;
typedef __attribute__((ext_vector_type(4))) float f32x4;

DI float u2f(uint32_t u){ union{uint32_t i;float f;}v; v.i=u; return v.f; }
DI uint16_t f2bf(float x){
  union{float f;uint32_t i;}v; v.f=x;
  uint32_t r = v.i + 0x7fffu + ((v.i>>16)&1u);
  return (uint16_t)(r>>16);
}
DI uint32_t pack2(float a, float b){
  return (uint32_t)f2bf(a) | ((uint32_t)f2bf(b) << 16);
}

DI int bsearch_row(const int* __restrict__ om, int M, int row){
  int lo = 0, hi = M;
  while (lo < hi){ int mid = (lo+hi)>>1; if (om[mid] < row) lo = mid+1; else hi = mid; }
  return (lo < M && om[lo] == row) ? lo : -1;
}

__global__ __launch_bounds__(256) void diag_kernel(float* __restrict__ out, long n, float c){
  long i = (long)blockIdx.x*256 + threadIdx.x;
  if (i < n) out[i] = c;
}

__global__ __launch_bounds__(256) void init_table_kernel(int* __restrict__ t, long n){
  long i = (long)blockIdx.x*256 + threadIdx.x;
  if (i < n) t[i] = -1;
}

__global__ __launch_bounds__(256) void build_table_kernel(
    const int* __restrict__ im, const int* __restrict__ om,
    int* __restrict__ tab, int M, int n_in, int n_out){
  const int k = blockIdx.y;
  long t = (long)blockIdx.x*256 + threadIdx.x;
  if (t >= M) return;
  int ii = im[(long)k*M + t];
  int oo = om[(long)k*M + t];
  if (ii >= 0 && ii < n_in && oo >= 0 && oo < n_out)
    tab[(long)k*n_out + oo] = ii;
}

// w (9,cin,128) fp32 -> wtb (9,128,cin) bf16 (transposed B rows).
__global__ __launch_bounds__(256) void prep_w_kernel(
    const float* __restrict__ w, uint16_t* __restrict__ wtb, int cin){
  long idx = (long)blockIdx.x*256 + threadIdx.x;
  long total = 9L*128*cin;
  if (idx >= total) return;
  int k = (int)(idx / (128*cin));
  int rem = (int)(idx % (128*cin));
  int cout = rem / cin, ci = rem % cin;
  wtb[idx] = f2bf(w[((long)k*cin + ci)*128 + cout]);
}

// c0 via table: thread = row; 9 table reads + 9 cached feat gathers + 576 FMA.
__global__ __launch_bounds__(256) void c0_tab_kernel(
    const float* __restrict__ feats, const float* __restrict__ w,
    const float* __restrict__ bias, const int* __restrict__ tab,
    uint16_t* __restrict__ out, int n_out){
  __shared__ float w_s[576];
  __shared__ float b_s[64];
  const int tid = threadIdx.x;
  for (int i = tid; i < 576; i += 256) w_s[i] = w[i];
  if (tid < 64) b_s[tid] = bias[tid];
  __syncthreads();
  long r = (long)blockIdx.x*256 + tid;
  if (r >= n_out) return;
  float f[9];
  #pragma unroll
  for (int k = 0; k < 9; k++){
    int gi = tab[(long)k*n_out + r];
    f[k] = (gi >= 0) ? feats[gi] : 0.f;
  }
  uint16_t* dst = out + r*64;
  #pragma unroll
  for (int c0 = 0; c0 < 64; c0 += 16){
    float a[16];
    #pragma unroll
    for (int j = 0; j < 16; j++) a[j] = b_s[c0+j];
    #pragma unroll
    for (int k = 0; k < 9; k++){
      float fk = f[k];
      #pragma unroll
      for (int j = 0; j < 16; j++) a[j] += fk * w_s[k*64 + c0 + j];
    }
    uint4 o0, o1;
    o0.x = pack2(a[0],a[1]);   o0.y = pack2(a[2],a[3]);
    o0.z = pack2(a[4],a[5]);   o0.w = pack2(a[6],a[7]);
    o1.x = pack2(a[8],a[9]);   o1.y = pack2(a[10],a[11]);
    o1.z = pack2(a[12],a[13]); o1.w = pack2(a[14],a[15]);
    *(uint4*)(dst + c0)     = o0;
    *(uint4*)(dst + c0 + 8) = o1;
  }
}

// c0 fallback (binary search), R5-proven.
__global__ __launch_bounds__(256) void gconv_c0_kernel(
    const float* __restrict__ feats, const float* __restrict__ w,
    const float* __restrict__ bias,
    const int* __restrict__ im, const int* __restrict__ om, int M,
    uint16_t* __restrict__ out, int n_in, int n_out){
  __shared__ float w_s[576];
  __shared__ int gi_s[36];
  const int tid = threadIdx.x;
  for (int i = tid; i < 576; i += 256) w_s[i] = w[i];
  const int base = blockIdx.x * 4;
  if (tid < 36){
    int p = tid / 9, k = tid - p*9;
    int row = base + p, gi = -1;
    if (row < n_out){
      int pos = bsearch_row(om + (long)k*M, M, row);
      if (pos >= 0){
        int ii = im[(long)k*M + pos];
        if (ii >= 0 && ii < n_in) gi = ii;
      }
    }
    gi_s[p*9 + k] = gi;
  }
  __syncthreads();
  int r4 = tid >> 6, c = tid & 63;
  int row = base + r4;
  if (row >= n_out) return;
  float a = bias[c];
  #pragma unroll
  for (int k = 0; k < 9; k++){
    int gi = gi_s[r4*9 + k];
    if (gi >= 0) a += feats[gi] * w_s[k*64 + c];
  }
  out[(long)row*64 + c] = f2bf(a);
}

// MFMA gather conv: CIN in {64,128} -> 128 couts. Block 128 rows x 128 couts.
template<int CIN, bool RELU, bool INBF, bool OUTBF>
__global__ __launch_bounds__(256,2) void mconv_kernel(
    const void* __restrict__ feats_v, const float* __restrict__ w,
    const uint16_t* __restrict__ wtb, int use_wtb,
    const float* __restrict__ bias,
    const int* __restrict__ im, const int* __restrict__ om, int M,
    const int* __restrict__ tab, int use_tab,
    void* __restrict__ out_v, int n_in, int n_out){
  const int tid = threadIdx.x;
  const int rb  = blockIdx.x * 128;
  constexpr int FS = CIN + 8;

  __shared__ __align__(16) uint16_t f_s[128*FS];
  __shared__ __align__(16) uint16_t wt_s[128*FS];
  __shared__ int gi_s[9*128];
  __shared__ int kval[9];

  if (tid < 9) kval[tid] = 0;
  __syncthreads();
  for (int idx = tid; idx < 9*128; idx += 256){
    int k = idx >> 7, r = idx & 127;
    int row = rb + r, gi = -1;
    if (row < n_out){
      if (use_tab){
        gi = tab[(long)k*n_out + row];
      } else {
        int pos = bsearch_row(om + (long)k*M, M, row);
        if (pos >= 0){
          int ii = im[(long)k*M + pos];
          if (ii >= 0 && ii < n_in) gi = ii;
        }
      }
    }
    gi_s[idx] = gi;
    if (gi >= 0) kval[k] = 1;     // benign race
  }
  __syncthreads();

  const int lane = tid & 63;
  const int wv   = tid >> 6;
  const int wr   = (wv & 1) * 64;
  const int wc   = (wv >> 1) * 64;
  const int l16  = lane & 15;
  const int quad = lane >> 4;

  f32x4 acc[4][4];
  #pragma unroll
  for (int i = 0; i < 4; i++)
    #pragma unroll
    for (int j = 0; j < 4; j++)
      acc[i][j] = (f32x4){0.f,0.f,0.f,0.f};

  for (int k = 0; k < 9; k++){
    if (!kval[k]) continue;
    if (use_wtb){
      const uint4* wg = (const uint4*)(wtb + (long)k*128*CIN);
      #pragma unroll
      for (int idx = tid; idx < 128*CIN/8; idx += 256){
        int cout = idx/(CIN/8), seg = idx%(CIN/8);
        *(uint4*)(&wt_s[cout*FS + seg*8]) = wg[idx];
      }
    } else {
      const float4* wg = (const float4*)(w + (long)k*CIN*128);
      #pragma unroll
      for (int idx = tid; idx < CIN*32; idx += 256){
        int ci = idx >> 5, c4 = (idx & 31)*4;
        float4 v = wg[idx];
        wt_s[(c4+0)*FS + ci] = f2bf(v.x);
        wt_s[(c4+1)*FS + ci] = f2bf(v.y);
        wt_s[(c4+2)*FS + ci] = f2bf(v.z);
        wt_s[(c4+3)*FS + ci] = f2bf(v.w);
      }
    }
    if (INBF){
      const uint16_t* f = (const uint16_t*)feats_v;
      #pragma unroll
      for (int idx = tid; idx < 128*CIN/8; idx += 256){
        int r = idx/(CIN/8), seg = idx%(CIN/8);
        int gi = gi_s[(k<<7)+r];
        uint4 v = make_uint4(0,0,0,0);
        if (gi >= 0) v = *(const uint4*)(f + (long)gi*CIN + seg*8);
        *(uint4*)(&f_s[r*FS + seg*8]) = v;
      }
    } else {
      const float* f = (const float*)feats_v;
      #pragma unroll
      for (int idx = tid; idx < 128*CIN/8; idx += 256){
        int r = idx/(CIN/8), seg = idx%(CIN/8);
        int gi = gi_s[(k<<7)+r];
        uint4 o = make_uint4(0,0,0,0);
        if (gi >= 0){
          float4 v0 = *(const float4*)(f + (long)gi*CIN + seg*8);
          float4 v1 = *(const float4*)(f + (long)gi*CIN + seg*8 + 4);
          o.x = pack2(v0.x,v0.y); o.y = pack2(v0.z,v0.w);
          o.z = pack2(v1.x,v1.y); o.w = pack2(v1.z,v1.w);
        }
        *(uint4*)(&f_s[r*FS + seg*8]) = o;
      }
    }
    __syncthreads();

    #pragma unroll
    for (int ch = 0; ch < CIN/32; ch++){
      bf16x8 af[4], bfr[4];
      #pragma unroll
      for (int t = 0; t < 4; t++){
        af[t]  = *(const bf16x8*)(&f_s [(wr + t*16 + l16)*FS + ch*32 + quad*8]);
        bfr[t] = *(const bf16x8*)(&wt_s[(wc + t*16 + l16)*FS + ch*32 + quad*8]);
      }
      #pragma unroll
      for (int rt = 0; rt < 4; rt++)
        #pragma unroll
        for (int ct = 0; ct < 4; ct++)
          acc[rt][ct] = __builtin_amdgcn_mfma_f32_16x16x32_bf16(
              af[rt], bfr[ct], acc[rt][ct], 0, 0, 0);
    }
    __syncthreads();
  }

  #pragma unroll
  for (int ct = 0; ct < 4; ct++){
    int cout = wc + ct*16 + l16;
    float bv = bias[cout];
    #pragma unroll
    for (int rt = 0; rt < 4; rt++){
      #pragma unroll
      for (int r = 0; r < 4; r++){
        int row = rb + wr + rt*16 + quad*4 + r;
        if (row < n_out){
          float v = acc[rt][ct][r] + bv;
          if (RELU) v = v > 0.f ? v : 0.f;
          if (OUTBF) ((uint16_t*)out_v)[(long)row*128 + cout] = f2bf(v);
          else       ((float*)   out_v)[(long)row*128 + cout] = v;
        }
      }
    }
  }
}

static inline long cdivl(long a, long b){ return (a + b - 1) / b; }

extern "C" void kernel_launch(void* const* d_in, const int* in_sizes, int n_in_args,
                              void* d_out, int out_size, void* d_ws, size_t ws_size,
                              hipStream_t stream) {
  const float* feats = (const float*)d_in[0];
  const float* w_c0 = (const float*)d_in[1];
  const float* b_c0 = (const float*)d_in[2];
  const int* in_c0  = (const int*)d_in[3];
  const int* out_c0 = (const int*)d_in[4];
  const float* w_d0 = (const float*)d_in[5];
  const float* b_d0 = (const float*)d_in[6];
  const int* in_d0  = (const int*)d_in[7];
  const int* out_d0 = (const int*)d_in[8];
  const float* w_c1 = (const float*)d_in[9];
  const float* b_c1 = (const float*)d_in[10];
  const int* in_c1  = (const int*)d_in[11];
  const int* out_c1 = (const int*)d_in[12];
  const float* w_d1 = (const float*)d_in[13];
  const float* b_d1 = (const float*)d_in[14];
  const int* in_d1  = (const int*)d_in[15];
  const int* out_d1 = (const int*)d_in[16];
  const float* w_c2 = (const float*)d_in[17];
  const float* b_c2 = (const float*)d_in[18];
  const int* in_c2  = (const int*)d_in[19];
  const int* out_c2 = (const int*)d_in[20];
  const float* w_d2 = (const float*)d_in[21];
  const float* b_d2 = (const float*)d_in[22];
  const int* in_d2  = (const int*)d_in[23];
  const int* out_d2 = (const int*)d_in[24];

  const int n0   = in_sizes[0];
  const int M_c0 = in_sizes[3]  / 9;
  const int M_d0 = in_sizes[7]  / 9;
  const int M_c1 = in_sizes[11] / 9;
  const int M_d1 = in_sizes[15] / 9;
  const int M_c2 = in_sizes[19] / 9;
  const int M_d2 = in_sizes[23] / 9;
  const int n1   = M_c1;
  const int n2   = M_c2;
  const int n3   = out_size/128 - n1 - n2;

  bool sane = n0 > 0 && out_size % 128 == 0 &&
              M_c0 > 0 && M_d0 > 0 && M_d1 > 0 && M_d2 > 0 &&
              n1 > 0 && n2 > 0 && n3 > 0;

  long maxElems = (long)n0*64;
  if ((long)n1*128 > maxElems) maxElems = (long)n1*128;
  if ((long)n2*128 > maxElems) maxElems = (long)n2*128;
  long fbytes = (maxElems*2 + 255)/256*256;
  long tbytes = (9L*n0*4 + 255)/256*256;          // max table (c0 layer)
  long wt64  = 9L*128*64, wt128 = 9L*128*128;
  long wbytes = (wt64 + 4*wt128) * 2;

  if (!sane || ws_size < (size_t)fbytes + 256){
    float C = (float)(16 + (int)std::min<size_t>(ws_size >> 20, (size_t)100000));
    if (!sane) C *= 1099511627776.0f;
    diag_kernel<<<cdivl(out_size,256),256,0,stream>>>((float*)d_out, out_size, C);
    return;
  }

  // ws: [ fbuf | table | wtb... ]  (later pieces optional)
  uint16_t* fbuf = (uint16_t*)d_ws;
  int* table = (int*)((char*)d_ws + fbytes);
  int use_tab = (ws_size >= (size_t)(fbytes + tbytes + 256)) ? 1 : 0;
  int use_wtb = (ws_size >= (size_t)(fbytes + tbytes + wbytes + 512)) ? 1 : 0;
  uint16_t* wtb_d0 = (uint16_t*)((char*)d_ws + fbytes + tbytes);
  uint16_t* wtb_c1 = wtb_d0 + wt64;
  uint16_t* wtb_d1 = wtb_c1 + wt128;
  uint16_t* wtb_c2 = wtb_d1 + wt128;
  uint16_t* wtb_d2 = wtb_c2 + wt128;

  float* out2 = (float*)d_out;
  float* out1 = out2 + (long)n3*128;
  float* out0 = out1 + (long)n2*128;
  uint16_t* x = fbuf; uint16_t* y = fbuf; uint16_t* z = fbuf;

  if (use_wtb){
    prep_w_kernel<<<cdivl(9L*128*64,256),256,0,stream>>>(w_d0, wtb_d0, 64);
    prep_w_kernel<<<cdivl(9L*128*128,256),256,0,stream>>>(w_c1, wtb_c1, 128);
    prep_w_kernel<<<cdivl(9L*128*128,256),256,0,stream>>>(w_d1, wtb_d1, 128);
    prep_w_kernel<<<cdivl(9L*128*128,256),256,0,stream>>>(w_c2, wtb_c2, 128);
    prep_w_kernel<<<cdivl(9L*128*128,256),256,0,stream>>>(w_d2, wtb_d2, 128);
  }

  auto make_tab = [&](const int* im, const int* om, int M, int n_in, int n_out){
    long n = 9L*n_out;
    init_table_kernel<<<cdivl(n,256),256,0,stream>>>(table, n);
    dim3 g((unsigned)cdivl(M,256), 9);
    build_table_kernel<<<g,256,0,stream>>>(im, om, table, M, n_in, n_out);
  };

  // c0: feats fp32 -> x bf16
  if (use_tab){
    make_tab(in_c0, out_c0, M_c0, n0, n0);
    c0_tab_kernel<<<cdivl(n0,256),256,0,stream>>>(feats, w_c0, b_c0, table, x, n0);
  } else {
    gconv_c0_kernel<<<cdivl(n0,4),256,0,stream>>>(
        feats, w_c0, b_c0, in_c0, out_c0, M_c0, x, n0, n0);
  }
  // d0: x bf16 -> out0 fp32, relu
  if (use_tab) make_tab(in_d0, out_d0, M_d0, n0, n1);
  mconv_kernel<64,true,true,false><<<cdivl(n1,128),256,0,stream>>>(
      x, w_d0, wtb_d0, use_wtb, b_d0, in_d0, out_d0, M_d0, table, use_tab, out0, n0, n1);
  // c1: out0 fp32 -> y bf16
  if (use_tab) make_tab(in_c1, out_c1, M_c1, n1, n1);
  mconv_kernel<128,false,false,true><<<cdivl(n1,128),256,0,stream>>>(
      out0, w_c1, wtb_c1, use_wtb, b_c1, in_c1, out_c1, M_c1, table, use_tab, y, n1, n1);
  // d1: y bf16 -> out1 fp32, relu
  if (use_tab) make_tab(in_d1, out_d1, M_d1, n1, n2);
  mconv_kernel<128,true,true,false><<<cdivl(n2,128),256,0,stream>>>(
      y, w_d1, wtb_d1, use_wtb, b_d1, in_d1, out_d1, M_d1, table, use_tab, out1, n1, n2);
  // c2: out1 fp32 -> z bf16
  if (use_tab) make_tab(in_c2, out_c2, M_c2, n2, n2);
  mconv_kernel<128,false,false,true><<<cdivl(n2,128),256,0,stream>>>(
      out1, w_c2, wtb_c2, use_wtb, b_c2, in_c2, out_c2, M_c2, table, use_tab, z, n2, n2);
  // d2: z bf16 -> out2 fp32
  if (use_tab) make_tab(in_d2, out_d2, M_d2, n2, n3);
  mconv_kernel<128,false,true,false><<<cdivl(n3,128),256,0,stream>>>(
      z, w_d2, wtb_d2, use_wtb, b_d2, in_d2, out_d2, M_d2, table, use_tab, out2, n2, n3);
}